// Round 4
// baseline (174.418 us; speedup 1.0000x reference)
//
#include <hip/hip_runtime.h>
#include <hip/hip_bf16.h>

// CfC / liquid-RNN scan on MFMA, R10 "split-8": 8 waves/group, 100% occupancy.
// R9 post-mortem: counters fit ~1.45GHz effective clock, step ~3200cy, issue
// ~1800cy/SIMD -> half issue-bound (trans!), half stall; occupancy grid-capped
// at 4 waves/SIMD. R10: 512-thr blocks (8 waves), 1024 blocks -> 8 waves/SIMD
// iff VGPR<=64 (launch_bounds(512,8)). Wave w: backbone m-tile w&3, half w>>2
// (2 MFMA partial, hi/lo split across wave pairs), head tile w (4 MFMA, 1 gate
// set). Trans/wave 20->10. Unified zbuf[lane][32B] = Z0|Z1 per consumer lane:
// the ((lq+2)&3) permutation is an involution -> producer lane == consumer
// lane for h (1 ds_write_b16); x loaded ONCE per block (waves 0-3, 1 ld/lane)
// instead of 8x replicated. 3 light barriers/step (partials, acts, h), all
// lgkmcnt-only (vmcnt never drained in loop). Phase-1 sum reassociated
// (hi-chain + lo-chain) -> absmax may drift a few ulp off 0.009765625.

#define CIN      16
#define UNITS    32
#define BACKBONE 64
#define CZ       48
#define TSTEPS   32
#define HW       4096
#define NPIX     16
#define NTHREADS 512

typedef __attribute__((ext_vector_type(8))) short  short8;
typedef __attribute__((ext_vector_type(8))) __bf16 bf16x8;
typedef __attribute__((ext_vector_type(4))) float  float4v;
typedef __attribute__((ext_vector_type(2))) float  float2v;
typedef __attribute__((ext_vector_type(4))) unsigned int uint4v;
typedef __attribute__((ext_vector_type(2))) unsigned int uint2v;

// LDS-only barrier: drain LDS pipe, sync waves; vmem stays in flight.
#define BAR_LDS() asm volatile("s_waitcnt lgkmcnt(0)\n\ts_barrier" ::: "memory")

__device__ __forceinline__ unsigned short bf16_rne(float f) {
    unsigned u = __float_as_uint(f);
    return (unsigned short)((u + 0x7FFFu + ((u >> 16) & 1u)) >> 16);
}
__device__ __forceinline__ float bf16_tof(unsigned short h) {
    return __uint_as_float(((unsigned)h) << 16);
}
// packed f32x2 -> bf16x2 (RNE), single VALU op
__device__ __forceinline__ unsigned cvt_pk_bf16(float lo, float hi) {
    unsigned r;
    asm("v_cvt_pk_bf16_f32 %0, %1, %2" : "=v"(r) : "v"(lo), "v"(hi));
    return r;
}

#if __has_builtin(__builtin_amdgcn_exp2f)
#define EXP2F(x) __builtin_amdgcn_exp2f(x)
#else
#define EXP2F(x) __expf(0.69314718056f * (x))
#endif
#if __has_builtin(__builtin_amdgcn_rcpf)
#define RCPF(x) __builtin_amdgcn_rcpf(x)
#else
#define RCPF(x) __fdividef(1.0f, (x))
#endif

// 1.7159*tanh(0.666*v) = 1.7159 - 3.4318/(2^(1.332*log2e*v)+1)
__device__ __forceinline__ float lecun_tanh_f(float v) {
    float e = EXP2F(1.92166925f * v);
    return fmaf(-3.4318f, RCPF(e + 1.0f), 1.7159f);
}
__device__ __forceinline__ float tanh_f(float v) {
    float e = EXP2F(2.88539008f * v);
    return fmaf(-2.0f, RCPF(e + 1.0f), 1.0f);
}
__device__ __forceinline__ float sigmoid_f(float v) {
    float e = EXP2F(-1.44269504f * v);
    return RCPF(1.0f + e);
}
__device__ __forceinline__ float4v mfma16(bf16x8 a, bf16x8 b, float4v c) {
    return __builtin_amdgcn_mfma_f32_16x16x32_bf16(a, b, c, 0, 0, 0);
}
__device__ __forceinline__ void split8(const float* v, bf16x8& hi, bf16x8& lo) {
    short8 sh, sl;
    #pragma unroll
    for (int j = 0; j < 8; ++j) {
        unsigned short h = bf16_rne(v[j]);
        sh[j] = (short)h;
        sl[j] = (short)bf16_rne(v[j] - bf16_tof(h));
    }
    hi = __builtin_bit_cast(bf16x8, sh);
    lo = __builtin_bit_cast(bf16x8, sl);
}

__global__ __launch_bounds__(NTHREADS, 8)
void cfc_mfma_kernel(const float* __restrict__ x,   const float* __restrict__ Wb,
                     const float* __restrict__ bb,
                     const float* __restrict__ Wff1, const float* __restrict__ bff1,
                     const float* __restrict__ Wff2, const float* __restrict__ bff2,
                     const float* __restrict__ Wta,  const float* __restrict__ bta,
                     const float* __restrict__ Wtb,  const float* __restrict__ btb,
                     float* __restrict__ out)
{
    // zbuf: per consumer-lane Z0|Z1 (8 dwords), 16B halves xor-swizzled by lane&1
    // abuf: per consumer-lane A2 frags (8 dwords), same swizzle
    // pbuf: phase-1 cross-half partials (2 floats per wave-lane)
    __shared__ __align__(16) unsigned zbuf[64 * 8];
    __shared__ __align__(16) unsigned abuf[64 * 8];
    __shared__ __align__(16) float    pbuf[8][64][2];

    const int tid  = threadIdx.x;
    const int w    = tid >> 6;          // wave id 0..7
    const int lane = tid & 63;
    const int ln   = lane & 15;         // MFMA m/n (pixel for B/C)
    const int lq   = lane >> 4;         // MFMA quad

    const int gpix = blockIdx.x * NPIX;
    const int b    = gpix >> 12;
    const int pinb = gpix & 4095;

    const int mt = w & 3;               // phase-1 m-tile
    const int hf = w >> 2;              // 0: hi half (+bias), 1: lo half

    // ---- phase-1 A frags: ONE half of backbone m-tile mt ------------------
    bf16x8 A1[2];
    #pragma unroll
    for (int kt = 0; kt < 2; ++kt) {
        float v[8];
        #pragma unroll
        for (int j = 0; j < 8; ++j) {
            int c = kt * 32 + lq * 8 + j;
            v[j] = (c < CZ) ? Wb[(mt * 16 + ln) * CZ + c] : 0.0f;
        }
        bf16x8 hi, lo;
        split8(v, hi, lo);
        A1[kt] = hf ? lo : hi;
    }
    float bbias[4];
    #pragma unroll
    for (int r = 0; r < 4; ++r) bbias[r] = bb[mt * 16 + lq * 4 + r];

    // ---- phase-2 A frags: head tile w (hi+lo), permuted rows/cols ---------
    // row m=ln of tile w -> unit (((ln>>2)+2)&3)*8 + w, head ln&3
    // col k -> backbone neuron n = 32kt + (j>>2)*16 + lq*4 + (j&3)
    const int head = ln & 3;
    const float* Whp = (head == 0) ? Wff1 : (head == 1) ? Wff2 : (head == 2) ? Wta : Wtb;
    const int urow = (((ln >> 2) + 2) & 3) * 8;
    bf16x8 Ah_hi[2], Ah_lo[2];
    #pragma unroll
    for (int kt = 0; kt < 2; ++kt) {
        float v[8];
        #pragma unroll
        for (int j = 0; j < 8; ++j) {
            int n = 32 * kt + (j >> 2) * 16 + lq * 4 + (j & 3);
            v[j] = Whp[(urow + w) * BACKBONE + n];
        }
        split8(v, Ah_hi[kt], Ah_lo[kt]);
    }
    // gate-side unit of THIS lane: ub + w (head = r in acc regs)
    const int ub = ((lq + 2) & 3) * 8;
    const int u2 = ub + w;
    float hbias[4];
    hbias[0] = bff1[u2]; hbias[1] = bff2[u2];
    hbias[2] = bta[u2];  hbias[3] = btb[u2];

    // ---- static LDS addresses ---------------------------------------------
    const int zr0 = lane * 8 + (lane & 1) * 4;            // Z0 16B chunk (dwords)
    const int zr1 = lane * 8 + ((lane & 1) ^ 1) * 4;      // Z1 16B chunk
    // h write: dword d_h of own lane's row; ushort index
    const int d_h  = ((lq < 2) ? 4 : 0) + (w >> 1);
    const int h_us = (lane * 8 + (((d_h >> 2) ^ (lane & 1)) << 2) + (d_h & 3)) * 2 + (w & 1);
    // acts write: dword i = mt*2 + hf of own lane's abuf row
    const int ai   = mt * 2 + hf;
    const int a_wr = lane * 8 + (((ai >> 2) ^ (lane & 1)) << 2) + (ai & 3);

    // x writer (waves 0-3): channel w*4+lq, pixel ln
    const int xch  = w * 4 + lq;
    const int cl   = (xch >> 3) * 16 + ln;                // consumer lane
    const int d_x  = (xch & 7) >> 1;                      // Z0 dword
    const int x_us = (cl * 8 + ((cl & 1) << 2) + d_x) * 2 + (xch & 1);
    const unsigned xidx = ((unsigned)(b * CIN + xch) * TSTEPS) * HW + (unsigned)(pinb + ln);

    // out offset (unit u2, pixel ln)
    const unsigned oo = ((unsigned)(b * UNITS + u2) * TSTEPS) * HW + (unsigned)(pinb + ln);

    // ---- prologue: zero zbuf (h0 + K-pad), stage x_0, prefetch x_1 --------
    zbuf[tid] = 0u;                     // 512 threads cover 512 dwords
    float xfa = 0.0f, xfb = 0.0f;
    if (w < 4) {
        xfa = x[xidx];                  // x_0
        xfb = x[xidx + HW];             // x_1 (in flight / reg)
    }
    __syncthreads();
    if (w < 4) {
        unsigned p0 = cvt_pk_bf16(xfa, xfa);
        ((unsigned short*)zbuf)[x_us] = (unsigned short)p0;
    }
    __syncthreads();

    unsigned toff = 0;

    // step t: consumes zbuf (x_t, h_t); writes x_{t+1} (from xcur reg) into
    // zbuf after BAR1; loads x_{t+2} into xnext; writes h_{t+1} before BAR3.
    auto step = [&](int t, float xcur, float& xnext) {
        // ---- read Z (2 swizzled b128) ----
        uint4v zv0 = *(const uint4v*)&zbuf[zr0];
        uint4v zv1 = *(const uint4v*)&zbuf[zr1];
        bf16x8 Z0 = __builtin_bit_cast(bf16x8, zv0);
        bf16x8 Z1 = __builtin_bit_cast(bf16x8, zv1);

        // ---- phase 1 partial: this wave's half (2 MFMA) ----
        float4v a;
        if (hf == 0) { a[0] = bbias[0]; a[1] = bbias[1]; a[2] = bbias[2]; a[3] = bbias[3]; }
        else         { a[0] = 0.f; a[1] = 0.f; a[2] = 0.f; a[3] = 0.f; }
        a = mfma16(A1[0], Z0, a);
        a = mfma16(A1[1], Z1, a);

        // publish the CROSS pair (what the partner needs)
        const int cp = hf ? 0 : 2;
        float2v pw = {a[cp], a[cp + 1]};
        *(float2v*)&pbuf[w][lane][0] = pw;
        BAR_LDS();                      // barrier 1: partials published

        // ---- x chores (waves 0-3): load x_{t+2}, stage x_{t+1} ----
        if (w < 4) {
            const int tl = (t + 2 < TSTEPS) ? t + 2 : TSTEPS - 1;
            xnext = x[xidx + (unsigned)tl * HW];
            unsigned px = cvt_pk_bf16(xcur, xcur);
            ((unsigned short*)zbuf)[x_us] = (unsigned short)px;
        }

        // ---- finish own pair, lecun, publish acts ----
        float2v pp = *(const float2v*)&pbuf[w ^ 4][lane][0];
        const int sp = hf ? 2 : 0;
        float s0 = a[sp]     + pp[0];
        float s1 = a[sp + 1] + pp[1];
        float g0 = lecun_tanh_f(s0);
        float g1 = lecun_tanh_f(s1);
        abuf[a_wr] = cvt_pk_bf16(g0, g1);
        BAR_LDS();                      // barrier 2: acts published

        // ---- read A2 (2 swizzled b128) ----
        uint4v w0 = *(const uint4v*)&abuf[zr0];
        uint4v w1 = *(const uint4v*)&abuf[zr1];
        bf16x8 A20 = __builtin_bit_cast(bf16x8, w0);
        bf16x8 A21 = __builtin_bit_cast(bf16x8, w1);

        // ---- phase 2: tile w (4 MFMA, same order as R9), gate, store ----
        float4v c;
        c[0] = hbias[0]; c[1] = hbias[1]; c[2] = hbias[2]; c[3] = hbias[3];
        c = mfma16(Ah_hi[0], A20, c);
        c = mfma16(Ah_lo[0], A20, c);
        c = mfma16(Ah_hi[1], A21, c);
        c = mfma16(Ah_lo[1], A21, c);
        float f1 = tanh_f(c[0]);
        float f2 = tanh_f(c[1]);
        float ti = sigmoid_f(c[2] + c[3]);
        float h  = fmaf(ti, f2 - f1, f1);
        out[oo + toff] = h;             // async store; never drained in loop
        unsigned hp = cvt_pk_bf16(h, h);
        ((unsigned short*)zbuf)[h_us] = (unsigned short)hp;
        BAR_LDS();                      // barrier 3: h (and x) ready for t+1
        toff += (unsigned)HW;
    };

    #pragma unroll 1
    for (int t = 0; t < TSTEPS; t += 2) {
        step(t,     xfb, xfa);          // writes x_{t+1}=xfb, loads x_{t+2}->xfa
        step(t + 1, xfa, xfb);          // ping-pong (static indexing, rule #20)
    }
}

extern "C" void kernel_launch(void* const* d_in, const int* in_sizes, int n_in,
                              void* d_out, int out_size, void* d_ws, size_t ws_size,
                              hipStream_t stream) {
    dim3 grid(4 * HW / NPIX);   // 1024 blocks x 8 waves -> 8 waves/SIMD
    cfc_mfma_kernel<<<grid, NTHREADS, 0, stream>>>(
        (const float*)d_in[0], (const float*)d_in[1], (const float*)d_in[2],
        (const float*)d_in[3], (const float*)d_in[4], (const float*)d_in[5],
        (const float*)d_in[6], (const float*)d_in[7], (const float*)d_in[8],
        (const float*)d_in[9], (const float*)d_in[10],
        (float*)d_out);
}